// Round 9
// baseline (289.739 us; speedup 1.0000x reference)
//
#include <hip/hip_runtime.h>
#include <hip/hip_bf16.h>
#include <hip/hip_fp16.h>

#define HID 64
#define NGRAPHS 64
#define BUCKET 64        // nodes per bucket (dst >> 6)
#define CAP 4096         // padded entry slots per bucket (mean occupancy ~1024)
#define EPB 4096         // edges per block in bin_scatter
#define NL_BLOCKS 512    // node_layer grid (2048 waves)

// ---------------------------------------------------------------------------
// Detect int64 vs int32 for edge_index / batch, AND init bucket cursors.
// flags[0]=edge is 64-bit, flags[1]=batch is 64-bit.
// ---------------------------------------------------------------------------
__global__ __launch_bounds__(256) void detect_init_kernel(const void* edge, const void* batch,
                                                          int* flags, int* bcursor,
                                                          int E2, int N, int G, int NB) {
    int t = threadIdx.x;
    for (int i = t; i < NB; i += 256) bcursor[i] = i * CAP;
    if (t < 64) {
        int lane = t;
        int half = E2 / 2;
        int stride = half / 64; if (stride < 1) stride = 1;
        int j = lane * stride; if (j >= half) j = half - 1;
        long long v = ((const long long*)edge)[j];
        bool ok = (v >= 0 && v < (long long)N);
        unsigned long long m = __ballot(ok);
        if (lane == 0) flags[0] = (m == ~0ULL) ? 1 : 0;
        int halfB = N / 2;
        int strideB = halfB / 64; if (strideB < 1) strideB = 1;
        int jb = lane * strideB; if (jb >= halfB) jb = halfB - 1;
        long long vb = ((const long long*)batch)[jb];
        bool okb = (vb >= 0 && vb < (long long)G);
        unsigned long long mb = __ballot(okb);
        if (lane == 0) flags[1] = (mb == ~0ULL) ? 1 : 0;
    }
}

__device__ __forceinline__ int idx_at(const void* p, int i, bool is64) {
    return is64 ? (int)((const long long*)p)[i] : ((const int*)p)[i];
}

// ---------------------------------------------------------------------------
// Bucket scatter into PADDED per-bucket regions: per-block LDS histogram ->
// one cursor reservation per bucket -> contiguous packed appends.
// entry = (src << 6) | (dst & 63). No prior count pass needed.
// ---------------------------------------------------------------------------
__global__ __launch_bounds__(256) void bin_scatter_kernel(const void* edge, const int* __restrict__ flags,
                                                          int* __restrict__ bcursor,
                                                          unsigned int* __restrict__ entries,
                                                          int E, int NB) {
    extern __shared__ int lds[];    // hist[NB] + base[NB]
    int* hist = lds;
    int* base = lds + NB;
    for (int i = threadIdx.x; i < NB; i += 256) hist[i] = 0;
    __syncthreads();
    bool is64 = flags[0] != 0;
    int start = blockIdx.x * EPB;
    int end = start + EPB; if (end > E) end = E;
    for (int e = start + threadIdx.x; e < end; e += 256) {
        int d = idx_at(edge, E + e, is64);
        atomicAdd(&hist[d >> 6], 1);
    }
    __syncthreads();
    for (int i = threadIdx.x; i < NB; i += 256) {
        int h = hist[i];
        base[i] = h ? atomicAdd(&bcursor[i], h) : 0;   // absolute position
    }
    __syncthreads();
    for (int i = threadIdx.x; i < NB; i += 256) hist[i] = 0;  // reuse as local cursor
    __syncthreads();
    for (int e = start + threadIdx.x; e < end; e += 256) {
        int srcv = idx_at(edge, e, is64);
        int d = idx_at(edge, E + e, is64);
        int b = d >> 6;
        int lo = atomicAdd(&hist[b], 1);
        int p = base[b] + lo;
        if (p < (b + 1) * CAP)   // overflow guard (statistically unreachable)
            entries[p] = ((unsigned int)srcv << 6) | (unsigned int)(d & 63);
    }
}

// ---------------------------------------------------------------------------
// Fused CSR finalize + LAYER 1. One block per bucket:
//  pass 1: histogram dests + accumulate x[src] into LDS (scalar feature)
//  wave 0: 64-lane scan -> rowptr (=absolute start in padded csr) + deg
//  pass 2: scatter src into csr within the bucket's padded window
//  phase 3: layer-1 transform for the bucket's 64 nodes ->
//           h1[i][f] = relu(mean1*W1l[f] + b1[f] + x_i*W1r[f]) + x_i  (+fp16)
// ---------------------------------------------------------------------------
__global__ __launch_bounds__(256) void csr_l1_kernel(const unsigned int* __restrict__ entries,
                                                     const int* __restrict__ bcursor,
                                                     const float* __restrict__ x,
                                                     const float* __restrict__ W1l,
                                                     const float* __restrict__ b1,
                                                     const float* __restrict__ W1r,
                                                     int* __restrict__ rowptr,
                                                     int* __restrict__ deg,
                                                     int* __restrict__ csr,
                                                     float* __restrict__ h1,
                                                     __half* __restrict__ h1h,
                                                     int N, int NB) {
    __shared__ int hist[BUCKET];
    __shared__ int lstart[BUCKET];
    __shared__ int lcur[BUCKET];
    __shared__ float accx[BUCKET];
    __shared__ float sx[BUCKET];
    int t = threadIdx.x;
    int b = blockIdx.x;
    int r0 = b * CAP;
    int cnt = bcursor[b] - r0; if (cnt > CAP) cnt = CAP;
    if (t < BUCKET) {
        hist[t] = 0; lcur[t] = 0; accx[t] = 0.0f;
        int node = b * BUCKET + t;
        sx[t] = (node < N) ? x[node] : 0.0f;
    }
    __syncthreads();
    for (int j = r0 + t; j < r0 + cnt; j += 256) {
        unsigned int en = entries[j];
        atomicAdd(&hist[en & 63u], 1);
        atomicAdd(&accx[en & 63u], x[en >> 6]);
    }
    __syncthreads();
    if (t < BUCKET) {  // wave 0: inclusive shuffle scan -> exclusive
        int v = hist[t];
        int s = v;
#pragma unroll
        for (int off = 1; off < 64; off <<= 1) {
            int u = __shfl_up(s, off);
            if (t >= off) s += u;
        }
        lstart[t] = s - v;
        int node = b * BUCKET + t;
        if (node < N) {
            rowptr[node] = r0 + s - v;
            deg[node] = v;
        }
    }
    __syncthreads();
    for (int j = r0 + t; j < r0 + cnt; j += 256) {
        unsigned int en = entries[j];
        int dl = (int)(en & 63u);
        int p = atomicAdd(&lcur[dl], 1);
        csr[r0 + lstart[dl] + p] = (int)(en >> 6);
    }
    __syncthreads();
    // Layer-1 transform: 4 subs x 64 features
    int f = t & 63;
    int sub = t >> 6;
    float wlf = W1l[f], bf = b1[f], wrf = W1r[f];
    for (int it = 0; it < 16; ++it) {
        int nl = it * 4 + sub;
        int node = b * BUCKET + nl;
        if (node < N) {
            int d = hist[nl];
            float mv = (d > 0) ? accx[nl] / (float)d : 0.0f;
            float xv = sx[nl];
            float v = fmaf(mv, wlf, fmaf(xv, wrf, bf));
            v = v > 0.0f ? v : 0.0f;
            float hv = v + xv;
            h1[(size_t)node * HID + f] = hv;
            h1h[(size_t)node * HID + f] = __float2half(hv);
        }
    }
}

// ---------------------------------------------------------------------------
// Layers 2/3 aggregation via gather on fp16 rows: 8 lanes per node, each lane
// one uint4 (16 B = 8 halfs). 4x unroll, dual accumulators. Mean written fp32.
// ---------------------------------------------------------------------------
__global__ __launch_bounds__(256) void gather_mean_kernel(const int* __restrict__ rowptr,
                                                          const int* __restrict__ deg,
                                                          const int* __restrict__ csr,
                                                          const __half* __restrict__ h,
                                                          float* __restrict__ mean, int N) {
    int grp = threadIdx.x >> 3;      // 32 groups per block
    int l = threadIdx.x & 7;         // lane within group -> 8 features
    int i = blockIdx.x * 32 + grp;
    if (i >= N) return;
    int r0 = rowptr[i];
    int d = deg[i];
    int r1 = r0 + d;
    float a0[8], a1[8];
#pragma unroll
    for (int k = 0; k < 8; ++k) { a0[k] = 0.0f; a1[k] = 0.0f; }
    int j = r0;
    for (; j + 4 <= r1; j += 4) {
        int s0 = csr[j], s1 = csr[j + 1], s2 = csr[j + 2], s3 = csr[j + 3];
        uint4 u0 = *(const uint4*)(h + (size_t)s0 * HID + l * 8);
        uint4 u1 = *(const uint4*)(h + (size_t)s1 * HID + l * 8);
        uint4 u2 = *(const uint4*)(h + (size_t)s2 * HID + l * 8);
        uint4 u3 = *(const uint4*)(h + (size_t)s3 * HID + l * 8);
        const __half2* p0 = (const __half2*)&u0;
        const __half2* p1 = (const __half2*)&u1;
        const __half2* p2 = (const __half2*)&u2;
        const __half2* p3 = (const __half2*)&u3;
#pragma unroll
        for (int q = 0; q < 4; ++q) {
            float2 f0 = __half22float2(p0[q]);
            float2 f1 = __half22float2(p1[q]);
            float2 f2 = __half22float2(p2[q]);
            float2 f3 = __half22float2(p3[q]);
            a0[2 * q]     += f0.x + f1.x;
            a0[2 * q + 1] += f0.y + f1.y;
            a1[2 * q]     += f2.x + f3.x;
            a1[2 * q + 1] += f2.y + f3.y;
        }
    }
    for (; j < r1; ++j) {
        int s = csr[j];
        uint4 u0 = *(const uint4*)(h + (size_t)s * HID + l * 8);
        const __half2* p0 = (const __half2*)&u0;
#pragma unroll
        for (int q = 0; q < 4; ++q) {
            float2 f0 = __half22float2(p0[q]);
            a0[2 * q] += f0.x;
            a0[2 * q + 1] += f0.y;
        }
    }
    float inv = (d > 0) ? 1.0f / (float)d : 0.0f;
    float4 o0, o1;
    o0.x = (a0[0] + a1[0]) * inv; o0.y = (a0[1] + a1[1]) * inv;
    o0.z = (a0[2] + a1[2]) * inv; o0.w = (a0[3] + a1[3]) * inv;
    o1.x = (a0[4] + a1[4]) * inv; o1.y = (a0[5] + a1[5]) * inv;
    o1.z = (a0[6] + a1[6]) * inv; o1.w = (a0[7] + a1[7]) * inv;
    float* mrow = mean + (size_t)i * HID + l * 8;
    *(float4*)(mrow) = o0;
    *(float4*)(mrow + 4) = o1;
}

// ---------------------------------------------------------------------------
// Layers 2/3 node transform — register-weight / scalar-row version.
// houth != nullptr -> also write fp16 copy (for next layer's gather).
// ---------------------------------------------------------------------------
__global__ __launch_bounds__(256) void node_layer_kernel(const float* __restrict__ hprev,
                                                         const float* __restrict__ mean,
                                                         const float* __restrict__ Wl,
                                                         const float* __restrict__ bvec,
                                                         const float* __restrict__ Wr,
                                                         float* __restrict__ hout,
                                                         __half* __restrict__ houth,
                                                         int N, int nwaves) {
    int f = threadIdx.x & 63;
    int wid = (blockIdx.x * blockDim.x + threadIdx.x) >> 6;
    float wl[HID], wr[HID];
#pragma unroll
    for (int k = 0; k < HID; ++k) {
        wl[k] = Wl[k * HID + f];
        wr[k] = Wr[k * HID + f];
    }
    float bf = bvec[f];
    for (int i = wid; i < N; i += nwaves) {
        int iu = __builtin_amdgcn_readfirstlane(i);
        const float* mrow = mean + (size_t)iu * HID;
        const float* hrow = hprev + (size_t)iu * HID;
        float hpv = hrow[f];
        float acc = bf;
#pragma unroll
        for (int k = 0; k < HID; ++k) {
            acc = fmaf(mrow[k], wl[k], acc);
            acc = fmaf(hrow[k], wr[k], acc);
        }
        float r = acc > 0.0f ? acc : 0.0f;
        float hv = r + hpv;
        hout[(size_t)iu * HID + f] = hv;
        if (houth) houth[(size_t)iu * HID + f] = __float2half(hv);
    }
}

// ---------------------------------------------------------------------------
// Fused global-mean-pool + FC head. batch is sorted: block g binary-searches
// its own node range, 4 waves sum it (coalesced rows), FC on wave 0.
// ---------------------------------------------------------------------------
__device__ __forceinline__ int lbound(const void* batch, int n, long long key, bool is64) {
    int lo = 0, hi = n;
    while (lo < hi) {
        int mid = (lo + hi) >> 1;
        long long v = is64 ? ((const long long*)batch)[mid] : (long long)((const int*)batch)[mid];
        if (v < key) lo = mid + 1; else hi = mid;
    }
    return lo;
}

__global__ __launch_bounds__(256) void pool_fc_kernel(const float* __restrict__ h,
                                                      const void* batch,
                                                      const int* __restrict__ flags,
                                                      const float* __restrict__ Wfc1,
                                                      const float* __restrict__ bfc1,
                                                      const float* __restrict__ Wfc2,
                                                      const float* __restrict__ bfc2,
                                                      float* __restrict__ out, int N) {
    __shared__ int sb[2];
    __shared__ float red[4][HID];
    __shared__ float mean[HID];
    int g = blockIdx.x;
    int t = threadIdx.x;
    bool is64 = flags[1] != 0;
    if (t == 0) sb[0] = lbound(batch, N, g, is64);
    if (t == 1) sb[1] = lbound(batch, N, g + 1, is64);
    __syncthreads();
    int s = sb[0], e = sb[1];
    int cnt = e - s;
    int f = t & 63, w = t >> 6;
    float acc = 0.0f;
    for (int i = s + w; i < e; i += 4) acc += h[(size_t)i * HID + f];
    red[w][f] = acc;
    __syncthreads();
    if (w == 0) {
        float m = (red[0][f] + red[1][f]) + (red[2][f] + red[3][f]);
        mean[f] = m / fmaxf((float)cnt, 1.0f);
    }
    __syncthreads();
    if (t < 64) {
        float v = 0.0f;
        if (t < 32) {
            float a = bfc1[t];
#pragma unroll
            for (int k = 0; k < HID; ++k) a += mean[k] * Wfc1[k * 32 + t];
            float hcc = a > 0.0f ? a : 0.0f;
            v = hcc * Wfc2[t];
        }
#pragma unroll
        for (int off = 32; off >= 1; off >>= 1) v += __shfl_down(v, off);
        if (t == 0) out[g] = v + bfc2[0];
    }
}

extern "C" void kernel_launch(void* const* d_in, const int* in_sizes, int n_in,
                              void* d_out, int out_size, void* d_ws, size_t ws_size,
                              hipStream_t stream) {
    const int N = in_sizes[0];       // 50000
    const int E2 = in_sizes[1];      // 2*E
    const int E = E2 / 2;
    const int NB = (N + BUCKET - 1) / BUCKET;   // 782

    const float* x    = (const float*)d_in[0];
    const void*  edge = d_in[1];
    const void*  batch= d_in[2];
    const float* W1l  = (const float*)d_in[3];
    const float* b1   = (const float*)d_in[4];
    const float* W1r  = (const float*)d_in[5];
    const float* W2l  = (const float*)d_in[6];
    const float* b2   = (const float*)d_in[7];
    const float* W2r  = (const float*)d_in[8];
    const float* W3l  = (const float*)d_in[9];
    const float* b3   = (const float*)d_in[10];
    const float* W3r  = (const float*)d_in[11];
    const float* Wfc1 = (const float*)d_in[12];
    const float* bfc1 = (const float*)d_in[13];
    const float* Wfc2 = (const float*)d_in[14];
    const float* bfc2 = (const float*)d_in[15];
    float* out = (float*)d_out;

    // Workspace layout (256 B aligned slices). NO memsets needed.
    char* ws = (char*)d_ws;
    size_t o = 0;
    auto alloc = [&](size_t bytes) { char* p = ws + o; o += (bytes + 255) & ~(size_t)255; return p; };
    int*   bcursor = (int*)alloc((size_t)NB * 4);
    unsigned int* entries = (unsigned int*)alloc((size_t)NB * CAP * 4);  // padded
    int*   csr     = (int*)alloc((size_t)NB * CAP * 4);                  // padded
    int*   rowptr  = (int*)alloc((size_t)N * 4);
    int*   deg     = (int*)alloc((size_t)N * 4);
    float* h1      = (float*)alloc((size_t)N * HID * 4);   // reused as h3
    float* meanb   = (float*)alloc((size_t)N * HID * 4);
    float* h2      = (float*)alloc((size_t)N * HID * 4);
    __half* h1h    = (__half*)alloc((size_t)N * HID * 2);  // fp16 copy for gather
    __half* h2h    = (__half*)alloc((size_t)N * HID * 2);
    int*   flags   = (int*)alloc(16);
    float* h3 = h1;

    // 1. Detect index dtype + init bucket cursors
    detect_init_kernel<<<1, 256, 0, stream>>>(edge, batch, flags, bcursor, E2, N, NGRAPHS, NB);

    // 2. Single-pass binned scatter into padded bucket regions
    const int nblk = (E + EPB - 1) / EPB;   // 196
    bin_scatter_kernel<<<nblk, 256, 2 * NB * 4, stream>>>(edge, flags, bcursor, entries, E, NB);

    // 3. Fused CSR finalize + layer 1
    csr_l1_kernel<<<NB, 256, 0, stream>>>(entries, bcursor, x, W1l, b1, W1r,
                                          rowptr, deg, csr, h1, h1h, N, NB);

    const int nlWaves = NL_BLOCKS * 4;

    // 4-5. Layer 2
    gather_mean_kernel<<<(N + 31) / 32, 256, 0, stream>>>(rowptr, deg, csr, h1h, meanb, N);
    node_layer_kernel<<<NL_BLOCKS, 256, 0, stream>>>(h1, meanb, W2l, b2, W2r, h2, h2h, N, nlWaves);

    // 6-7. Layer 3 (no fp16 copy needed — nothing gathers from h3)
    gather_mean_kernel<<<(N + 31) / 32, 256, 0, stream>>>(rowptr, deg, csr, h2h, meanb, N);
    node_layer_kernel<<<NL_BLOCKS, 256, 0, stream>>>(h2, meanb, W3l, b3, W3r, h3, (__half*)nullptr, N, nlWaves);

    // 8. Fused pool + FC head
    pool_fc_kernel<<<NGRAPHS, 256, 0, stream>>>(h3, batch, flags, Wfc1, bfc1, Wfc2, bfc2, out, N);
}

// Round 10
// 269.564 us; speedup vs baseline: 1.0748x; 1.0748x over previous
//
#include <hip/hip_runtime.h>
#include <hip/hip_bf16.h>
#include <hip/hip_fp16.h>

#define HID 64
#define NGRAPHS 64
#define BUCKET 64        // nodes per bucket (dst >> 6)
#define CAP 4096         // padded entry slots per bucket (mean occupancy ~1024)
#define EPB 4096         // edges per block in bin_scatter
#define NL_BLOCKS 512    // node_layer grid (2048 waves)

// ---------------------------------------------------------------------------
// Detect int64 vs int32 for edge_index / batch, init bucket cursors, and
// zero psum/gcnt (pool accumulators). One small dispatch, no memsets.
// ---------------------------------------------------------------------------
__global__ __launch_bounds__(256) void detect_init_kernel(const void* edge, const void* batch,
                                                          int* flags, int* bcursor,
                                                          float* psum, int* gcnt,
                                                          int E2, int N, int G, int NB) {
    int t = threadIdx.x;
    for (int i = t; i < NB; i += 256) bcursor[i] = i * CAP;
    for (int i = t; i < G * HID; i += 256) psum[i] = 0.0f;
    for (int i = t; i < G; i += 256) gcnt[i] = 0;
    if (t < 64) {
        int lane = t;
        int half = E2 / 2;
        int stride = half / 64; if (stride < 1) stride = 1;
        int j = lane * stride; if (j >= half) j = half - 1;
        long long v = ((const long long*)edge)[j];
        bool ok = (v >= 0 && v < (long long)N);
        unsigned long long m = __ballot(ok);
        if (lane == 0) flags[0] = (m == ~0ULL) ? 1 : 0;
        int halfB = N / 2;
        int strideB = halfB / 64; if (strideB < 1) strideB = 1;
        int jb = lane * strideB; if (jb >= halfB) jb = halfB - 1;
        long long vb = ((const long long*)batch)[jb];
        bool okb = (vb >= 0 && vb < (long long)G);
        unsigned long long mb = __ballot(okb);
        if (lane == 0) flags[1] = (mb == ~0ULL) ? 1 : 0;
    }
}

__device__ __forceinline__ int idx_at(const void* p, int i, bool is64) {
    return is64 ? (int)((const long long*)p)[i] : ((const int*)p)[i];
}

// ---------------------------------------------------------------------------
// Bucket scatter into PADDED per-bucket regions: per-block LDS histogram ->
// one cursor reservation per bucket -> contiguous packed appends.
// entry = (src << 6) | (dst & 63). No prior count pass needed.
// ---------------------------------------------------------------------------
__global__ __launch_bounds__(256) void bin_scatter_kernel(const void* edge, const int* __restrict__ flags,
                                                          int* __restrict__ bcursor,
                                                          unsigned int* __restrict__ entries,
                                                          int E, int NB) {
    extern __shared__ int lds[];    // hist[NB] + base[NB]
    int* hist = lds;
    int* base = lds + NB;
    for (int i = threadIdx.x; i < NB; i += 256) hist[i] = 0;
    __syncthreads();
    bool is64 = flags[0] != 0;
    int start = blockIdx.x * EPB;
    int end = start + EPB; if (end > E) end = E;
    for (int e = start + threadIdx.x; e < end; e += 256) {
        int d = idx_at(edge, E + e, is64);
        atomicAdd(&hist[d >> 6], 1);
    }
    __syncthreads();
    for (int i = threadIdx.x; i < NB; i += 256) {
        int h = hist[i];
        base[i] = h ? atomicAdd(&bcursor[i], h) : 0;   // absolute position
    }
    __syncthreads();
    for (int i = threadIdx.x; i < NB; i += 256) hist[i] = 0;  // reuse as local cursor
    __syncthreads();
    for (int e = start + threadIdx.x; e < end; e += 256) {
        int srcv = idx_at(edge, e, is64);
        int d = idx_at(edge, E + e, is64);
        int b = d >> 6;
        int lo = atomicAdd(&hist[b], 1);
        int p = base[b] + lo;
        if (p < (b + 1) * CAP)   // overflow guard (statistically unreachable)
            entries[p] = ((unsigned int)srcv << 6) | (unsigned int)(d & 63);
    }
}

// ---------------------------------------------------------------------------
// Fused CSR finalize + LAYER 1. One block per bucket:
//  pass 1: histogram dests + accumulate x[src] into LDS (scalar feature)
//  wave 0: 64-lane scan -> rowptr (=absolute start in padded csr) + deg
//  pass 2: scatter src into csr within the bucket's padded window
//  phase 3: layer-1 transform -> h1 (fp32 + fp16)
// ---------------------------------------------------------------------------
__global__ __launch_bounds__(256) void csr_l1_kernel(const unsigned int* __restrict__ entries,
                                                     const int* __restrict__ bcursor,
                                                     const float* __restrict__ x,
                                                     const float* __restrict__ W1l,
                                                     const float* __restrict__ b1,
                                                     const float* __restrict__ W1r,
                                                     int* __restrict__ rowptr,
                                                     int* __restrict__ deg,
                                                     int* __restrict__ csr,
                                                     float* __restrict__ h1,
                                                     __half* __restrict__ h1h,
                                                     int N, int NB) {
    __shared__ int hist[BUCKET];
    __shared__ int lstart[BUCKET];
    __shared__ int lcur[BUCKET];
    __shared__ float accx[BUCKET];
    __shared__ float sx[BUCKET];
    int t = threadIdx.x;
    int b = blockIdx.x;
    int r0 = b * CAP;
    int cnt = bcursor[b] - r0; if (cnt > CAP) cnt = CAP;
    if (t < BUCKET) {
        hist[t] = 0; lcur[t] = 0; accx[t] = 0.0f;
        int node = b * BUCKET + t;
        sx[t] = (node < N) ? x[node] : 0.0f;
    }
    __syncthreads();
    for (int j = r0 + t; j < r0 + cnt; j += 256) {
        unsigned int en = entries[j];
        atomicAdd(&hist[en & 63u], 1);
        atomicAdd(&accx[en & 63u], x[en >> 6]);
    }
    __syncthreads();
    if (t < BUCKET) {  // wave 0: inclusive shuffle scan -> exclusive
        int v = hist[t];
        int s = v;
#pragma unroll
        for (int off = 1; off < 64; off <<= 1) {
            int u = __shfl_up(s, off);
            if (t >= off) s += u;
        }
        lstart[t] = s - v;
        int node = b * BUCKET + t;
        if (node < N) {
            rowptr[node] = r0 + s - v;
            deg[node] = v;
        }
    }
    __syncthreads();
    for (int j = r0 + t; j < r0 + cnt; j += 256) {
        unsigned int en = entries[j];
        int dl = (int)(en & 63u);
        int p = atomicAdd(&lcur[dl], 1);
        csr[r0 + lstart[dl] + p] = (int)(en >> 6);
    }
    __syncthreads();
    // Layer-1 transform: 4 subs x 64 features
    int f = t & 63;
    int sub = t >> 6;
    float wlf = W1l[f], bf = b1[f], wrf = W1r[f];
    for (int it = 0; it < 16; ++it) {
        int nl = it * 4 + sub;
        int node = b * BUCKET + nl;
        if (node < N) {
            int d = hist[nl];
            float mv = (d > 0) ? accx[nl] / (float)d : 0.0f;
            float xv = sx[nl];
            float v = fmaf(mv, wlf, fmaf(xv, wrf, bf));
            v = v > 0.0f ? v : 0.0f;
            float hv = v + xv;
            h1[(size_t)node * HID + f] = hv;
            h1h[(size_t)node * HID + f] = __float2half(hv);
        }
    }
}

// ---------------------------------------------------------------------------
// Layers 2/3 aggregation via gather on fp16 rows: 8 lanes per node, each lane
// one uint4 (16 B = 8 halfs). 4x unroll, dual accumulators. Mean written fp32.
// ---------------------------------------------------------------------------
__global__ __launch_bounds__(256) void gather_mean_kernel(const int* __restrict__ rowptr,
                                                          const int* __restrict__ deg,
                                                          const int* __restrict__ csr,
                                                          const __half* __restrict__ h,
                                                          float* __restrict__ mean, int N) {
    int grp = threadIdx.x >> 3;      // 32 groups per block
    int l = threadIdx.x & 7;         // lane within group -> 8 features
    int i = blockIdx.x * 32 + grp;
    if (i >= N) return;
    int r0 = rowptr[i];
    int d = deg[i];
    int r1 = r0 + d;
    float a0[8], a1[8];
#pragma unroll
    for (int k = 0; k < 8; ++k) { a0[k] = 0.0f; a1[k] = 0.0f; }
    int j = r0;
    for (; j + 4 <= r1; j += 4) {
        int s0 = csr[j], s1 = csr[j + 1], s2 = csr[j + 2], s3 = csr[j + 3];
        uint4 u0 = *(const uint4*)(h + (size_t)s0 * HID + l * 8);
        uint4 u1 = *(const uint4*)(h + (size_t)s1 * HID + l * 8);
        uint4 u2 = *(const uint4*)(h + (size_t)s2 * HID + l * 8);
        uint4 u3 = *(const uint4*)(h + (size_t)s3 * HID + l * 8);
        const __half2* p0 = (const __half2*)&u0;
        const __half2* p1 = (const __half2*)&u1;
        const __half2* p2 = (const __half2*)&u2;
        const __half2* p3 = (const __half2*)&u3;
#pragma unroll
        for (int q = 0; q < 4; ++q) {
            float2 f0 = __half22float2(p0[q]);
            float2 f1 = __half22float2(p1[q]);
            float2 f2 = __half22float2(p2[q]);
            float2 f3 = __half22float2(p3[q]);
            a0[2 * q]     += f0.x + f1.x;
            a0[2 * q + 1] += f0.y + f1.y;
            a1[2 * q]     += f2.x + f3.x;
            a1[2 * q + 1] += f2.y + f3.y;
        }
    }
    for (; j < r1; ++j) {
        int s = csr[j];
        uint4 u0 = *(const uint4*)(h + (size_t)s * HID + l * 8);
        const __half2* p0 = (const __half2*)&u0;
#pragma unroll
        for (int q = 0; q < 4; ++q) {
            float2 f0 = __half22float2(p0[q]);
            a0[2 * q] += f0.x;
            a0[2 * q + 1] += f0.y;
        }
    }
    float inv = (d > 0) ? 1.0f / (float)d : 0.0f;
    float4 o0, o1;
    o0.x = (a0[0] + a1[0]) * inv; o0.y = (a0[1] + a1[1]) * inv;
    o0.z = (a0[2] + a1[2]) * inv; o0.w = (a0[3] + a1[3]) * inv;
    o1.x = (a0[4] + a1[4]) * inv; o1.y = (a0[5] + a1[5]) * inv;
    o1.z = (a0[6] + a1[6]) * inv; o1.w = (a0[7] + a1[7]) * inv;
    float* mrow = mean + (size_t)i * HID + l * 8;
    *(float4*)(mrow) = o0;
    *(float4*)(mrow + 4) = o1;
}

// ---------------------------------------------------------------------------
// Layers 2/3 node transform — register-weight / scalar-row version.
// houth != nullptr -> also write fp16 copy (for next layer's gather).
// ---------------------------------------------------------------------------
__global__ __launch_bounds__(256) void node_layer_kernel(const float* __restrict__ hprev,
                                                         const float* __restrict__ mean,
                                                         const float* __restrict__ Wl,
                                                         const float* __restrict__ bvec,
                                                         const float* __restrict__ Wr,
                                                         float* __restrict__ hout,
                                                         __half* __restrict__ houth,
                                                         int N, int nwaves) {
    int f = threadIdx.x & 63;
    int wid = (blockIdx.x * blockDim.x + threadIdx.x) >> 6;
    float wl[HID], wr[HID];
#pragma unroll
    for (int k = 0; k < HID; ++k) {
        wl[k] = Wl[k * HID + f];
        wr[k] = Wr[k * HID + f];
    }
    float bf = bvec[f];
    for (int i = wid; i < N; i += nwaves) {
        int iu = __builtin_amdgcn_readfirstlane(i);
        const float* mrow = mean + (size_t)iu * HID;
        const float* hrow = hprev + (size_t)iu * HID;
        float hpv = hrow[f];
        float acc = bf;
#pragma unroll
        for (int k = 0; k < HID; ++k) {
            acc = fmaf(mrow[k], wl[k], acc);
            acc = fmaf(hrow[k], wr[k], acc);
        }
        float r = acc > 0.0f ? acc : 0.0f;
        float hv = r + hpv;
        hout[(size_t)iu * HID + f] = hv;
        if (houth) houth[(size_t)iu * HID + f] = __float2half(hv);
    }
}

// ---------------------------------------------------------------------------
// Global mean pool: batch sorted -> run-length accumulate per wave (782
// waves), one atomic per (graph-run, feature). Proven ~10 µs shape.
// ---------------------------------------------------------------------------
__global__ __launch_bounds__(256) void pool_kernel(const float* __restrict__ h,
                                                   const void* batch,
                                                   const int* __restrict__ flags,
                                                   float* __restrict__ psum,
                                                   int* __restrict__ gcnt,
                                                   int N, int nodesPerWave) {
    int wave = (blockIdx.x * blockDim.x + threadIdx.x) >> 6;
    int f = threadIdx.x & 63;
    int start = wave * nodesPerWave;
    if (start >= N) return;
    bool is64 = flags[1] != 0;
    int end = start + nodesPerWave;
    if (end > N) end = N;
    int g = idx_at(batch, start, is64);
    float acc = 0.0f;
    int c = 0;
    for (int i = start; i < end; ++i) {
        int gi = idx_at(batch, i, is64);
        if (gi != g) {
            atomicAdd(&psum[g * HID + f], acc);
            if (f == 0) atomicAdd(&gcnt[g], c);
            acc = 0.0f; c = 0; g = gi;
        }
        acc += h[(size_t)i * HID + f];
        c++;
    }
    atomicAdd(&psum[g * HID + f], acc);
    if (f == 0) atomicAdd(&gcnt[g], c);
}

// ---------------------------------------------------------------------------
// FC head: one block (64 threads) per graph.
// ---------------------------------------------------------------------------
__global__ __launch_bounds__(64) void fc_kernel(const float* __restrict__ psum,
                                                const int* __restrict__ gcnt,
                                                const float* __restrict__ Wfc1,
                                                const float* __restrict__ bfc1,
                                                const float* __restrict__ Wfc2,
                                                const float* __restrict__ bfc2,
                                                float* __restrict__ out) {
    int g = blockIdx.x;
    int t = threadIdx.x;
    __shared__ float mean[HID];
    float c = fmaxf((float)gcnt[g], 1.0f);
    mean[t] = psum[g * HID + t] / c;
    __syncthreads();
    float v = 0.0f;
    if (t < 32) {
        float acc = bfc1[t];
#pragma unroll
        for (int k = 0; k < HID; ++k) acc += mean[k] * Wfc1[k * 32 + t];
        float hcc = acc > 0.0f ? acc : 0.0f;
        v = hcc * Wfc2[t];
    }
#pragma unroll
    for (int off = 32; off >= 1; off >>= 1) v += __shfl_down(v, off);
    if (t == 0) out[g] = v + bfc2[0];
}

extern "C" void kernel_launch(void* const* d_in, const int* in_sizes, int n_in,
                              void* d_out, int out_size, void* d_ws, size_t ws_size,
                              hipStream_t stream) {
    const int N = in_sizes[0];       // 50000
    const int E2 = in_sizes[1];      // 2*E
    const int E = E2 / 2;
    const int NB = (N + BUCKET - 1) / BUCKET;   // 782

    const float* x    = (const float*)d_in[0];
    const void*  edge = d_in[1];
    const void*  batch= d_in[2];
    const float* W1l  = (const float*)d_in[3];
    const float* b1   = (const float*)d_in[4];
    const float* W1r  = (const float*)d_in[5];
    const float* W2l  = (const float*)d_in[6];
    const float* b2   = (const float*)d_in[7];
    const float* W2r  = (const float*)d_in[8];
    const float* W3l  = (const float*)d_in[9];
    const float* b3   = (const float*)d_in[10];
    const float* W3r  = (const float*)d_in[11];
    const float* Wfc1 = (const float*)d_in[12];
    const float* bfc1 = (const float*)d_in[13];
    const float* Wfc2 = (const float*)d_in[14];
    const float* bfc2 = (const float*)d_in[15];
    float* out = (float*)d_out;

    // Workspace layout (256 B aligned slices). No host-side memsets.
    char* ws = (char*)d_ws;
    size_t o = 0;
    auto alloc = [&](size_t bytes) { char* p = ws + o; o += (bytes + 255) & ~(size_t)255; return p; };
    int*   bcursor = (int*)alloc((size_t)NB * 4);
    float* psum    = (float*)alloc((size_t)NGRAPHS * HID * 4);
    int*   gcnt    = (int*)alloc((size_t)NGRAPHS * 4);
    unsigned int* entries = (unsigned int*)alloc((size_t)NB * CAP * 4);  // padded
    int*   csr     = (int*)alloc((size_t)NB * CAP * 4);                  // padded
    int*   rowptr  = (int*)alloc((size_t)N * 4);
    int*   deg     = (int*)alloc((size_t)N * 4);
    float* h1      = (float*)alloc((size_t)N * HID * 4);   // reused as h3
    float* meanb   = (float*)alloc((size_t)N * HID * 4);
    float* h2      = (float*)alloc((size_t)N * HID * 4);
    __half* h1h    = (__half*)alloc((size_t)N * HID * 2);  // fp16 copy for gather
    __half* h2h    = (__half*)alloc((size_t)N * HID * 2);
    int*   flags   = (int*)alloc(16);
    float* h3 = h1;

    // 1. Detect index dtype + init bucket cursors + zero pool accumulators
    detect_init_kernel<<<1, 256, 0, stream>>>(edge, batch, flags, bcursor, psum, gcnt,
                                              E2, N, NGRAPHS, NB);

    // 2. Single-pass binned scatter into padded bucket regions
    const int nblk = (E + EPB - 1) / EPB;   // 196
    bin_scatter_kernel<<<nblk, 256, 2 * NB * 4, stream>>>(edge, flags, bcursor, entries, E, NB);

    // 3. Fused CSR finalize + layer 1
    csr_l1_kernel<<<NB, 256, 0, stream>>>(entries, bcursor, x, W1l, b1, W1r,
                                          rowptr, deg, csr, h1, h1h, N, NB);

    const int nlWaves = NL_BLOCKS * 4;

    // 4-5. Layer 2
    gather_mean_kernel<<<(N + 31) / 32, 256, 0, stream>>>(rowptr, deg, csr, h1h, meanb, N);
    node_layer_kernel<<<NL_BLOCKS, 256, 0, stream>>>(h1, meanb, W2l, b2, W2r, h2, h2h, N, nlWaves);

    // 6-7. Layer 3 (no fp16 copy needed — nothing gathers from h3)
    gather_mean_kernel<<<(N + 31) / 32, 256, 0, stream>>>(rowptr, deg, csr, h2h, meanb, N);
    node_layer_kernel<<<NL_BLOCKS, 256, 0, stream>>>(h2, meanb, W3l, b3, W3r, h3, (__half*)nullptr, N, nlWaves);

    // 8. Wave-parallel pool (batch sorted -> run-length + atomics)
    {
        int nodesPerWave = 64;
        int waves = (N + nodesPerWave - 1) / nodesPerWave;
        int threads = waves * 64;
        pool_kernel<<<(threads + 255) / 256, 256, 0, stream>>>(h3, batch, flags, psum, gcnt,
                                                               N, nodesPerWave);
    }
    // 9. FC head
    fc_kernel<<<NGRAPHS, 64, 0, stream>>>(psum, gcnt, Wfc1, bfc1, Wfc2, bfc2, out);
}